// Round 9
// baseline (592.150 us; speedup 1.0000x reference)
//
#include <hip/hip_runtime.h>
#include <hip/hip_bf16.h>

#define N_USERC 50000
#define N_ITEMC 50000
#define NTOT    100000
#define NNZC    3200000
#define EMBC    64
#define BATCHC  4096
#define NSLOT   (3*BATCHC)
#define NBKT    196            // buckets of 512 rows
typedef unsigned long long u64;

typedef __attribute__((ext_vector_type(4))) float floatx4;
typedef __attribute__((ext_vector_type(4))) int   intx4;
typedef __attribute__((ext_vector_type(8))) short shortx8;   // 8 bf16 = 4 VGPRs

__device__ __forceinline__ float bf2f(unsigned short u) {
    return __int_as_float(((int)u) << 16);
}
__device__ __forceinline__ unsigned short f2bf(float f) {
    __hip_bfloat16 h = __float2bfloat16(f);      // RTNE
    return *(unsigned short*)&h;
}

// ---------------- init: xb = bf16(concat(user_emb, item_emb)) ----------------
__global__ void k_init_xb(const float4* __restrict__ ue, const float4* __restrict__ ie,
                          ushort4* __restrict__ xb) {
    long i = (long)blockIdx.x * blockDim.x + threadIdx.x;
    const long nu4 = (long)N_USERC * EMBC / 4;
    const long tot4 = (long)NTOT * EMBC / 4;
    if (i < tot4) {
        float4 v = (i < nu4) ? ue[i] : ie[i - nu4];
        ushort4 b; b.x = f2bf(v.x); b.y = f2bf(v.y); b.z = f2bf(v.z); b.w = f2bf(v.w);
        xb[i] = b;
    }
}

__global__ void k_zero_bcnt(int* bcnt) {
    if (threadIdx.x < NBKT + 1) bcnt[threadIdx.x] = 0;
}

// ---------------- prep: W^T in bf16 (dense 64x64) + summed bias, all 3 layers ----------------
__global__ void k_prep_w(const float* __restrict__ Wgc, const float* __restrict__ Wbi,
                         const float* __restrict__ bgc, const float* __restrict__ bbi,
                         unsigned short* __restrict__ wgT, unsigned short* __restrict__ wbT,
                         float* __restrict__ biasSum) {
    int tid = threadIdx.x;
    for (int k = 0; k < 3; k++) {
        for (int i = tid; i < 4096; i += 256) {
            int d = i >> 6, c = i & 63;
            wgT[k * 4096 + c * 64 + d] = f2bf(Wgc[k * 4096 + i]);
            wbT[k * 4096 + c * 64 + d] = f2bf(Wbi[k * 4096 + i]);
        }
        if (tid < 64) biasSum[k * 64 + tid] = bgc[k * 64 + tid] + bbi[k * 64 + tid];
    }
}

// ---------------- pack edges to 8B (row|col|bf16val) + LDS bucket histogram ----------------
__global__ __launch_bounds__(256) void k_packB(const intx4* __restrict__ row4, const intx4* __restrict__ col4,
                                               const floatx4* __restrict__ val4, int* __restrict__ bcnt,
                                               u64* __restrict__ pe) {
    __shared__ int bh[NBKT];
    int tid = threadIdx.x;
    for (int i = tid; i < NBKT; i += 256) bh[i] = 0;
    __syncthreads();
    int i = blockIdx.x * 256 + tid;          // group of 4 edges
    if (i < NNZC / 4) {
        intx4 r = __builtin_nontemporal_load(row4 + i);
        intx4 c = __builtin_nontemporal_load(col4 + i);
        floatx4 v = __builtin_nontemporal_load(val4 + i);
        atomicAdd(&bh[r.x >> 9], 1);
        atomicAdd(&bh[r.y >> 9], 1);
        atomicAdd(&bh[r.z >> 9], 1);
        atomicAdd(&bh[r.w >> 9], 1);
        u64 p0 = ((u64)r.x << 33) | ((u64)(unsigned)c.x << 16) | f2bf(v.x);
        u64 p1 = ((u64)r.y << 33) | ((u64)(unsigned)c.y << 16) | f2bf(v.y);
        u64 p2 = ((u64)r.z << 33) | ((u64)(unsigned)c.z << 16) | f2bf(v.z);
        u64 p3 = ((u64)r.w << 33) | ((u64)(unsigned)c.w << 16) | f2bf(v.w);
        u64* dst = pe + (long)i * 4;
        dst[0] = p0; dst[1] = p1; dst[2] = p2; dst[3] = p3;
    }
    __syncthreads();
    for (int b = tid; b < NBKT; b += 256)
        if (bh[b] > 0) atomicAdd(&bcnt[b], bh[b]);
}

// ---------------- scan 196 bucket counts -> bases; init cursors ----------------
__global__ void k_bktscan(const int* __restrict__ bcnt, int* __restrict__ bbase0,
                          int* __restrict__ gbcur) {
    __shared__ int sm[256];
    int t = threadIdx.x;
    int v = (t < NBKT) ? bcnt[t] : 0;
    sm[t] = v;
    __syncthreads();
    for (int off = 1; off < 256; off <<= 1) {
        int u = (t >= off) ? sm[t - off] : 0;
        __syncthreads();
        sm[t] += u;
        __syncthreads();
    }
    if (t < NBKT) {
        int base = sm[t] - v;   // exclusive
        bbase0[t] = base;
        gbcur[t] = base;
    }
    if (t == 0) bbase0[NBKT] = NNZC;
}

// ---------------- bucket partition: block-bulk reservation ----------------
__global__ __launch_bounds__(256) void k_scatterB(const u64* __restrict__ pe, int* __restrict__ gbcur,
                                                  u64* __restrict__ eb) {
    __shared__ int bh[NBKT], bbase[NBKT], bcur[NBKT];
    int tid = threadIdx.x;
    for (int i = tid; i < NBKT; i += 256) { bh[i] = 0; bcur[i] = 0; }
    __syncthreads();
    long base = (long)blockIdx.x * 4096;
    u64 e[16]; int bk[16];
    #pragma unroll
    for (int i = 0; i < 16; i++) {
        long idx = base + i * 256 + tid;
        if (idx < NNZC) {
            e[i] = __builtin_nontemporal_load(pe + idx);
            bk[i] = (int)(e[i] >> 42);      // row >> 9
            atomicAdd(&bh[bk[i]], 1);
        } else bk[i] = -1;
    }
    __syncthreads();
    for (int i = tid; i < NBKT; i += 256)
        if (bh[i] > 0) bbase[i] = atomicAdd(&gbcur[i], bh[i]);
    __syncthreads();
    #pragma unroll
    for (int i = 0; i < 16; i++) {
        if (bk[i] >= 0) {
            int p = bbase[bk[i]] + atomicAdd(&bcur[bk[i]], 1);
            eb[p] = e[i];
        }
    }
}

// ---------------- bucket -> row-CSR + rp build: one block per bucket ----------------
__global__ __launch_bounds__(256) void k_csrC(const u64* __restrict__ eb, const int* __restrict__ bbase0,
                                              int* __restrict__ rp, u64* __restrict__ ecv) {
    __shared__ int lhist[512];
    __shared__ int lcur[512];
    __shared__ int sm[256];
    int b = blockIdx.x;
    int tid = threadIdx.x;
    int row0 = b << 9;
    lhist[tid] = 0; lhist[tid + 256] = 0;
    __syncthreads();
    int start = bbase0[b];
    int end = bbase0[b + 1];
    // pass 1: histogram rows within bucket
    for (int e = start + tid; e < end; e += 256) {
        u64 w = eb[e];
        int rl = (int)(w >> 33) - row0;
        atomicAdd(&lhist[rl], 1);
    }
    __syncthreads();
    // scan 512 with 256 threads (2 consecutive elems per thread)
    int h0 = lhist[2 * tid], h1 = lhist[2 * tid + 1];
    int pair = h0 + h1;
    sm[tid] = pair;
    __syncthreads();
    for (int off = 1; off < 256; off <<= 1) {
        int u = (tid >= off) ? sm[tid - off] : 0;
        __syncthreads();
        sm[tid] += u;
        __syncthreads();
    }
    int pairExcl = sm[tid] - pair;
    int e0 = start + pairExcl;
    int e1 = e0 + h0;
    lcur[2 * tid] = e0;
    lcur[2 * tid + 1] = e1;
    int rg0 = row0 + 2 * tid, rg1 = rg0 + 1;
    if (rg0 < NTOT) rp[rg0] = e0;
    if (rg1 < NTOT) rp[rg1] = e1;
    if (b == NBKT - 1 && tid == 0) rp[NTOT] = NNZC;
    __syncthreads();
    // pass 2: place edges
    for (int e = start + tid; e < end; e += 256) {
        u64 w = eb[e];
        int rl = (int)(w >> 33) - row0;
        u64 col = (w >> 16) & 0x1FFFF;
        u64 vbf = w & 0xFFFF;
        int p = atomicAdd(&lcur[rl], 1);
        ecv[p] = (vbf << 48) | col;   // high32 = f32 bits of bf16 val, low32 = col
    }
}

// ---------------- SpMM: one wave per row, 32 edges/step (16 lanes per edge, 8 deep) ----------------
__global__ __launch_bounds__(256) void k_spmm(const int* __restrict__ rp, const long* __restrict__ ecv,
                                              const unsigned short* __restrict__ xb,
                                              unsigned short* __restrict__ side_bf) {
    int r = (blockIdx.x * blockDim.x + threadIdx.x) >> 6;
    int lane = threadIdx.x & 63;
    if (r >= NTOT) return;
    int q = lane >> 4;
    int t4 = (lane & 15) * 4;
    int s = rp[r], e = rp[r + 1];
    float a0 = 0.f, a1 = 0.f, a2 = 0.f, a3 = 0.f;
    for (int j = s; j < e; j += 32) {
        long pk[8];
        bool vm[8];
        #pragma unroll
        for (int u = 0; u < 8; ++u) {
            int je = j + u * 4 + q;
            vm[u] = (je < e);
            pk[u] = __builtin_nontemporal_load(ecv + (vm[u] ? je : s));
        }
        ushort4 xv[8];
        #pragma unroll
        for (int u = 0; u < 8; ++u)
            xv[u] = *(const ushort4*)(xb + (long)(int)pk[u] * EMBC + t4);
        #pragma unroll
        for (int u = 0; u < 8; ++u) {
            float w = vm[u] ? __int_as_float((int)(pk[u] >> 32)) : 0.f;
            a0 += w * bf2f(xv[u].x);
            a1 += w * bf2f(xv[u].y);
            a2 += w * bf2f(xv[u].z);
            a3 += w * bf2f(xv[u].w);
        }
    }
    a0 += __shfl_xor(a0, 16); a1 += __shfl_xor(a1, 16); a2 += __shfl_xor(a2, 16); a3 += __shfl_xor(a3, 16);
    a0 += __shfl_xor(a0, 32); a1 += __shfl_xor(a1, 32); a2 += __shfl_xor(a2, 32); a3 += __shfl_xor(a3, 32);
    if (lane < 16) {
        ushort4 o; o.x = f2bf(a0); o.y = f2bf(a1); o.z = f2bf(a2); o.w = f2bf(a3);
        *(ushort4*)(side_bf + (long)r * EMBC + t4) = o;
    }
}

// ------------- MFMA layer: [sum_emb + bi_emb + bias] -> leaky_relu, updates xb (bf16 state) -------------
#define RPB 128
#define LDP 72
__global__ __launch_bounds__(256) void k_layer_mfma(
    const unsigned short* __restrict__ side_bf, unsigned short* __restrict__ xb,
    const unsigned short* __restrict__ wgT, const unsigned short* __restrict__ wbT,
    const float* __restrict__ biasSum)
{
    __shared__ unsigned short sS[RPB * LDP];
    __shared__ unsigned short sM[RPB * LDP];
    __shared__ unsigned short sWg[64 * LDP];
    __shared__ unsigned short sWb[64 * LDP];
    __shared__ float sBias[64];

    int tid = threadIdx.x;
    int row0 = blockIdx.x * RPB;

    // stage pre-transposed W: 64 rows x 8 chunks of 8 shorts, per matrix
    #pragma unroll
    for (int it = 0; it < 2; ++it) {
        int item = it * 256 + tid;          // 0..511
        int c = item >> 3, ch = item & 7;
        *(uint4*)(sWg + c * LDP + ch * 8) = *(const uint4*)(wgT + c * 64 + ch * 8);
        *(uint4*)(sWb + c * LDP + ch * 8) = *(const uint4*)(wbT + c * 64 + ch * 8);
    }
    if (tid < 64) sBias[tid] = biasSum[tid];

    #pragma unroll
    for (int it = 0; it < (RPB * 8) / 256; ++it) {
        int item = it * 256 + tid;
        int r = item >> 3, ch = item & 7;
        long grow = row0 + r;
        uint4 sv = make_uint4(0, 0, 0, 0), ev = make_uint4(0, 0, 0, 0);
        if (grow < NTOT) {
            sv = *(const uint4*)(side_bf + grow * 64 + ch * 8);
            ev = *(const uint4*)(xb + grow * 64 + ch * 8);
        }
        uint4 mv;
        mv.x = f2bf(bf2f(ev.x & 0xffff) * bf2f(sv.x & 0xffff)) |
               ((unsigned int)f2bf(bf2f(ev.x >> 16) * bf2f(sv.x >> 16)) << 16);
        mv.y = f2bf(bf2f(ev.y & 0xffff) * bf2f(sv.y & 0xffff)) |
               ((unsigned int)f2bf(bf2f(ev.y >> 16) * bf2f(sv.y >> 16)) << 16);
        mv.z = f2bf(bf2f(ev.z & 0xffff) * bf2f(sv.z & 0xffff)) |
               ((unsigned int)f2bf(bf2f(ev.z >> 16) * bf2f(sv.z >> 16)) << 16);
        mv.w = f2bf(bf2f(ev.w & 0xffff) * bf2f(sv.w & 0xffff)) |
               ((unsigned int)f2bf(bf2f(ev.w >> 16) * bf2f(sv.w >> 16)) << 16);
        *(uint4*)(sS + r * LDP + ch * 8) = sv;
        *(uint4*)(sM + r * LDP + ch * 8) = mv;
    }
    __syncthreads();

    int wave = tid >> 6, lane = tid & 63;
    int quad = lane >> 4, l16 = lane & 15;

    floatx4 accG[2][4], accB[2][4];
    #pragma unroll
    for (int rt = 0; rt < 2; rt++)
        #pragma unroll
        for (int ct = 0; ct < 4; ct++) {
            accG[rt][ct] = (floatx4){0.f, 0.f, 0.f, 0.f};
            accB[rt][ct] = (floatx4){0.f, 0.f, 0.f, 0.f};
        }

    #pragma unroll
    for (int kc = 0; kc < 64; kc += 32) {
        shortx8 aS[2], aM[2];
        #pragma unroll
        for (int rt = 0; rt < 2; rt++) {
            int r = wave * 32 + rt * 16 + l16;
            aS[rt] = *(const shortx8*)(sS + r * LDP + kc + quad * 8);
            aM[rt] = *(const shortx8*)(sM + r * LDP + kc + quad * 8);
        }
        #pragma unroll
        for (int ct = 0; ct < 4; ct++) {
            int c = ct * 16 + l16;
            shortx8 bG = *(const shortx8*)(sWg + c * LDP + kc + quad * 8);
            shortx8 bB = *(const shortx8*)(sWb + c * LDP + kc + quad * 8);
            #pragma unroll
            for (int rt = 0; rt < 2; rt++) {
                accG[rt][ct] = __builtin_amdgcn_mfma_f32_16x16x32_bf16(aS[rt], bG, accG[rt][ct], 0, 0, 0);
                accB[rt][ct] = __builtin_amdgcn_mfma_f32_16x16x32_bf16(aM[rt], bB, accB[rt][ct], 0, 0, 0);
            }
        }
    }

    #pragma unroll
    for (int rt = 0; rt < 2; rt++)
        #pragma unroll
        for (int ct = 0; ct < 4; ct++) {
            int c = ct * 16 + l16;
            float bs = sBias[c];
            #pragma unroll
            for (int reg = 0; reg < 4; reg++) {
                int r = wave * 32 + rt * 16 + quad * 4 + reg;
                long grow = row0 + r;
                if (grow < NTOT) {
                    float v = accG[rt][ct][reg] + accB[rt][ct][reg] + bs;
                    float o = (v > 0.f) ? v : 0.2f * v;
                    xb[grow * 64 + c] = f2bf(o);
                }
            }
        }
}

// ------------- gather batch rows (optionally L2-normalized) into d_out -------------
__global__ __launch_bounds__(256) void k_gather(const unsigned short* __restrict__ xb,
                                                const int* __restrict__ users,
                                                const int* __restrict__ pos,
                                                const int* __restrict__ neg,
                                                float* __restrict__ out, int colOff, int normalize) {
    int slot = (blockIdx.x * blockDim.x + threadIdx.x) >> 6;
    int lane = threadIdx.x & 63;
    if (slot >= NSLOT) return;
    int row;
    if (slot < BATCHC)          row = users[slot];
    else if (slot < 2 * BATCHC) row = N_USERC + pos[slot - BATCHC];
    else                        row = N_USERC + neg[slot - 2 * BATCHC];
    float v = bf2f(xb[(long)row * 64 + lane]);
    if (normalize) {
        float ss = v * v;
        for (int off = 32; off > 0; off >>= 1) ss += __shfl_xor(ss, off);
        float nrm = fmaxf(sqrtf(ss), 1e-12f);
        v = v / nrm;
    }
    out[(long)slot * 256 + colOff + lane] = v;
}

extern "C" void kernel_launch(void* const* d_in, const int* in_sizes, int n_in,
                              void* d_out, int out_size, void* d_ws, size_t ws_size,
                              hipStream_t stream) {
    const int*   users   = (const int*)d_in[0];
    const int*   pos     = (const int*)d_in[1];
    const int*   neg     = (const int*)d_in[2];
    const int*   adj_row = (const int*)d_in[3];
    const int*   adj_col = (const int*)d_in[4];
    const float* adj_val = (const float*)d_in[5];
    const float* user_emb = (const float*)d_in[6];
    const float* item_emb = (const float*)d_in[7];
    const float* W_gc = (const float*)d_in[8];
    const float* b_gc = (const float*)d_in[9];
    const float* W_bi = (const float*)d_in[10];
    const float* b_bi = (const float*)d_in[11];
    float* out = (float*)d_out;

    // workspace carve-up (~78 MB); ecv aliases pe (pe dead after k_scatterB)
    char* p = (char*)d_ws;
    u64*  pe  = (u64*)p;                        p += (size_t)NNZC * 8;   // packed edges / final CSR
    u64*  ecv = pe;
    u64*  eb  = (u64*)p;                        p += (size_t)NNZC * 8;   // bucket-grouped edges
    unsigned short* side_bf = (unsigned short*)p; p += (size_t)NTOT * EMBC * 2;
    unsigned short* xb = (unsigned short*)p;    p += (size_t)NTOT * EMBC * 2;
    int*  rp  = (int*)p;                        p += (size_t)(NTOT + 1) * 4 + 60;
    int*  bcnt = (int*)p;                       p += 1024;
    int*  bbase0 = (int*)p;                     p += 1024;
    int*  gbcur = (int*)p;                      p += 1024;
    unsigned short* wgT = (unsigned short*)p;   p += 3 * 4096 * 2;
    unsigned short* wbT = (unsigned short*)p;   p += 3 * 4096 * 2;
    float* biasSum = (float*)p;                 p += 3 * 64 * 4;

    k_init_xb<<<(NTOT * EMBC / 4 + 255) / 256, 256, 0, stream>>>(
        (const float4*)user_emb, (const float4*)item_emb, (ushort4*)xb);

    k_prep_w<<<1, 256, 0, stream>>>(W_gc, W_bi, b_gc, b_bi, wgT, wbT, biasSum);

    k_zero_bcnt<<<1, 256, 0, stream>>>(bcnt);
    k_packB<<<(NNZC / 4 + 255) / 256, 256, 0, stream>>>(
        (const intx4*)adj_row, (const intx4*)adj_col, (const floatx4*)adj_val, bcnt, pe);
    k_bktscan<<<1, 256, 0, stream>>>(bcnt, bbase0, gbcur);
    k_scatterB<<<(NNZC + 4095) / 4096, 256, 0, stream>>>(pe, gbcur, eb);
    k_csrC<<<NBKT, 256, 0, stream>>>(eb, bbase0, rp, ecv);

    // layer-0 slice of all_embs = raw ego (no normalization)
    k_gather<<<(NSLOT * 64 + 255) / 256, 256, 0, stream>>>(xb, users, pos, neg, out, 0, 0);

    const int NB_LAYER = (NTOT + RPB - 1) / RPB;
    for (int k = 0; k < 3; k++) {
        k_spmm<<<NTOT / 4, 256, 0, stream>>>(rp, (const long*)ecv, xb, side_bf);
        k_layer_mfma<<<NB_LAYER, 256, 0, stream>>>(side_bf, xb,
            wgT + (size_t)k * 4096, wbT + (size_t)k * 4096, biasSum + (size_t)k * 64);
        k_gather<<<(NSLOT * 64 + 255) / 256, 256, 0, stream>>>(xb, users, pos, neg, out, 64 * (k + 1), 1);
    }
}

// Round 10
// 563.293 us; speedup vs baseline: 1.0512x; 1.0512x over previous
//
#include <hip/hip_runtime.h>
#include <hip/hip_bf16.h>

#define N_USERC 50000
#define N_ITEMC 50000
#define NTOT    100000
#define NNZC    3200000
#define EMBC    64
#define BATCHC  4096
#define NSLOT   (3*BATCHC)
#define NBKT    196            // buckets of 512 rows
typedef unsigned long long u64;

typedef __attribute__((ext_vector_type(4))) float floatx4;
typedef __attribute__((ext_vector_type(4))) int   intx4;
typedef __attribute__((ext_vector_type(8))) short shortx8;   // 8 bf16 = 4 VGPRs

__device__ __forceinline__ float bf2f(unsigned short u) {
    return __int_as_float(((int)u) << 16);
}
__device__ __forceinline__ unsigned short f2bf(float f) {
    __hip_bfloat16 h = __float2bfloat16(f);      // RTNE
    return *(unsigned short*)&h;
}

// ---------------- fused init: xb = bf16(ego); last block: W^T prep + zero bcnt ----------------
#define NB_INIT (NTOT * EMBC / 4 / 256)   // 6250
__global__ void k_init(const float4* __restrict__ ue, const float4* __restrict__ ie,
                       ushort4* __restrict__ xb,
                       const float* __restrict__ Wgc, const float* __restrict__ Wbi,
                       const float* __restrict__ bgc, const float* __restrict__ bbi,
                       unsigned short* __restrict__ wgT, unsigned short* __restrict__ wbT,
                       float* __restrict__ biasSum, int* __restrict__ bcnt) {
    int tid = threadIdx.x;
    if (blockIdx.x < NB_INIT) {
        long i = (long)blockIdx.x * 256 + tid;
        const long nu4 = (long)N_USERC * EMBC / 4;
        float4 v = (i < nu4) ? ue[i] : ie[i - nu4];
        ushort4 b; b.x = f2bf(v.x); b.y = f2bf(v.y); b.z = f2bf(v.z); b.w = f2bf(v.w);
        xb[i] = b;
    } else {
        for (int k = 0; k < 3; k++) {
            for (int i = tid; i < 4096; i += 256) {
                int d = i >> 6, c = i & 63;
                wgT[k * 4096 + c * 64 + d] = f2bf(Wgc[k * 4096 + i]);
                wbT[k * 4096 + c * 64 + d] = f2bf(Wbi[k * 4096 + i]);
            }
            if (tid < 64) biasSum[k * 64 + tid] = bgc[k * 64 + tid] + bbi[k * 64 + tid];
        }
        if (tid < NBKT + 1) bcnt[tid] = 0;
    }
}

// ---------------- pack edges to 8B (row|col|bf16val) + LDS bucket histogram ----------------
__global__ __launch_bounds__(256) void k_packB(const intx4* __restrict__ row4, const intx4* __restrict__ col4,
                                               const floatx4* __restrict__ val4, int* __restrict__ bcnt,
                                               u64* __restrict__ pe) {
    __shared__ int bh[NBKT];
    int tid = threadIdx.x;
    for (int i = tid; i < NBKT; i += 256) bh[i] = 0;
    __syncthreads();
    int i = blockIdx.x * 256 + tid;          // group of 4 edges
    if (i < NNZC / 4) {
        intx4 r = __builtin_nontemporal_load(row4 + i);
        intx4 c = __builtin_nontemporal_load(col4 + i);
        floatx4 v = __builtin_nontemporal_load(val4 + i);
        atomicAdd(&bh[r.x >> 9], 1);
        atomicAdd(&bh[r.y >> 9], 1);
        atomicAdd(&bh[r.z >> 9], 1);
        atomicAdd(&bh[r.w >> 9], 1);
        u64 p0 = ((u64)r.x << 33) | ((u64)(unsigned)c.x << 16) | f2bf(v.x);
        u64 p1 = ((u64)r.y << 33) | ((u64)(unsigned)c.y << 16) | f2bf(v.y);
        u64 p2 = ((u64)r.z << 33) | ((u64)(unsigned)c.z << 16) | f2bf(v.z);
        u64 p3 = ((u64)r.w << 33) | ((u64)(unsigned)c.w << 16) | f2bf(v.w);
        u64* dst = pe + (long)i * 4;
        dst[0] = p0; dst[1] = p1; dst[2] = p2; dst[3] = p3;
    }
    __syncthreads();
    for (int b = tid; b < NBKT; b += 256)
        if (bh[b] > 0) atomicAdd(&bcnt[b], bh[b]);
}

// ---------------- scan 196 bucket counts -> bases; init cursors ----------------
__global__ void k_bktscan(const int* __restrict__ bcnt, int* __restrict__ bbase0,
                          int* __restrict__ gbcur) {
    __shared__ int sm[256];
    int t = threadIdx.x;
    int v = (t < NBKT) ? bcnt[t] : 0;
    sm[t] = v;
    __syncthreads();
    for (int off = 1; off < 256; off <<= 1) {
        int u = (t >= off) ? sm[t - off] : 0;
        __syncthreads();
        sm[t] += u;
        __syncthreads();
    }
    if (t < NBKT) {
        int base = sm[t] - v;   // exclusive
        bbase0[t] = base;
        gbcur[t] = base;
    }
    if (t == 0) bbase0[NBKT] = NNZC;
}

// ---------------- bucket partition: block-bulk reservation ----------------
__global__ __launch_bounds__(256) void k_scatterB(const u64* __restrict__ pe, int* __restrict__ gbcur,
                                                  u64* __restrict__ eb) {
    __shared__ int bh[NBKT], bbase[NBKT], bcur[NBKT];
    int tid = threadIdx.x;
    for (int i = tid; i < NBKT; i += 256) { bh[i] = 0; bcur[i] = 0; }
    __syncthreads();
    long base = (long)blockIdx.x * 4096;
    u64 e[16]; int bk[16];
    #pragma unroll
    for (int i = 0; i < 16; i++) {
        long idx = base + i * 256 + tid;
        if (idx < NNZC) {
            e[i] = __builtin_nontemporal_load(pe + idx);
            bk[i] = (int)(e[i] >> 42);      // row >> 9
            atomicAdd(&bh[bk[i]], 1);
        } else bk[i] = -1;
    }
    __syncthreads();
    for (int i = tid; i < NBKT; i += 256)
        if (bh[i] > 0) bbase[i] = atomicAdd(&gbcur[i], bh[i]);
    __syncthreads();
    #pragma unroll
    for (int i = 0; i < 16; i++) {
        if (bk[i] >= 0) {
            int p = bbase[bk[i]] + atomicAdd(&bcur[bk[i]], 1);
            eb[p] = e[i];
        }
    }
}

// ---------------- bucket -> row-CSR + rp build: one block per bucket ----------------
__global__ __launch_bounds__(256) void k_csrC(const u64* __restrict__ eb, const int* __restrict__ bbase0,
                                              int* __restrict__ rp, u64* __restrict__ ecv) {
    __shared__ int lhist[512];
    __shared__ int lcur[512];
    __shared__ int sm[256];
    int b = blockIdx.x;
    int tid = threadIdx.x;
    int row0 = b << 9;
    lhist[tid] = 0; lhist[tid + 256] = 0;
    __syncthreads();
    int start = bbase0[b];
    int end = bbase0[b + 1];
    for (int e = start + tid; e < end; e += 256) {
        u64 w = eb[e];
        int rl = (int)(w >> 33) - row0;
        atomicAdd(&lhist[rl], 1);
    }
    __syncthreads();
    int h0 = lhist[2 * tid], h1 = lhist[2 * tid + 1];
    int pair = h0 + h1;
    sm[tid] = pair;
    __syncthreads();
    for (int off = 1; off < 256; off <<= 1) {
        int u = (tid >= off) ? sm[tid - off] : 0;
        __syncthreads();
        sm[tid] += u;
        __syncthreads();
    }
    int pairExcl = sm[tid] - pair;
    int e0 = start + pairExcl;
    int e1 = e0 + h0;
    lcur[2 * tid] = e0;
    lcur[2 * tid + 1] = e1;
    int rg0 = row0 + 2 * tid, rg1 = rg0 + 1;
    if (rg0 < NTOT) rp[rg0] = e0;
    if (rg1 < NTOT) rp[rg1] = e1;
    if (b == NBKT - 1 && tid == 0) rp[NTOT] = NNZC;
    __syncthreads();
    for (int e = start + tid; e < end; e += 256) {
        u64 w = eb[e];
        int rl = (int)(w >> 33) - row0;
        u64 col = (w >> 16) & 0x1FFFF;
        u64 vbf = w & 0xFFFF;
        int p = atomicAdd(&lcur[rl], 1);
        ecv[p] = (vbf << 48) | col;
    }
}

// ---------------- SpMM (R8 form): one wave per row, 16 edges/step (16 lanes per edge) ----------------
__global__ __launch_bounds__(256) void k_spmm(const int* __restrict__ rp, const long* __restrict__ ecv,
                                              const unsigned short* __restrict__ xb,
                                              unsigned short* __restrict__ side_bf) {
    int r = (blockIdx.x * blockDim.x + threadIdx.x) >> 6;
    int lane = threadIdx.x & 63;
    if (r >= NTOT) return;
    int q = lane >> 4;
    int t4 = (lane & 15) * 4;
    int s = rp[r], e = rp[r + 1];
    float a0 = 0.f, a1 = 0.f, a2 = 0.f, a3 = 0.f;
    for (int j = s; j < e; j += 16) {
        long pk[4];
        bool vm[4];
        #pragma unroll
        for (int u = 0; u < 4; ++u) {
            int je = j + u * 4 + q;
            vm[u] = (je < e);
            pk[u] = __builtin_nontemporal_load(ecv + (vm[u] ? je : s));
        }
        ushort4 xv[4];
        #pragma unroll
        for (int u = 0; u < 4; ++u)
            xv[u] = *(const ushort4*)(xb + (long)(int)pk[u] * EMBC + t4);
        #pragma unroll
        for (int u = 0; u < 4; ++u) {
            float w = vm[u] ? __int_as_float((int)(pk[u] >> 32)) : 0.f;
            a0 += w * bf2f(xv[u].x);
            a1 += w * bf2f(xv[u].y);
            a2 += w * bf2f(xv[u].z);
            a3 += w * bf2f(xv[u].w);
        }
    }
    a0 += __shfl_xor(a0, 16); a1 += __shfl_xor(a1, 16); a2 += __shfl_xor(a2, 16); a3 += __shfl_xor(a3, 16);
    a0 += __shfl_xor(a0, 32); a1 += __shfl_xor(a1, 32); a2 += __shfl_xor(a2, 32); a3 += __shfl_xor(a3, 32);
    if (lane < 16) {
        ushort4 o; o.x = f2bf(a0); o.y = f2bf(a1); o.z = f2bf(a2); o.w = f2bf(a3);
        *(ushort4*)(side_bf + (long)r * EMBC + t4) = o;
    }
}

// ------------- MFMA layer; epilogue routed through LDS for vectorized stores -------------
#define RPB 128
#define LDP 72
__global__ __launch_bounds__(256) void k_layer_mfma(
    const unsigned short* __restrict__ side_bf, unsigned short* __restrict__ xb,
    const unsigned short* __restrict__ wgT, const unsigned short* __restrict__ wbT,
    const float* __restrict__ biasSum)
{
    __shared__ unsigned short sS[RPB * LDP];
    __shared__ unsigned short sM[RPB * LDP];
    __shared__ unsigned short sWg[64 * LDP];
    __shared__ unsigned short sWb[64 * LDP];
    __shared__ float sBias[64];

    int tid = threadIdx.x;
    int row0 = blockIdx.x * RPB;

    #pragma unroll
    for (int it = 0; it < 2; ++it) {
        int item = it * 256 + tid;          // 0..511
        int c = item >> 3, ch = item & 7;
        *(uint4*)(sWg + c * LDP + ch * 8) = *(const uint4*)(wgT + c * 64 + ch * 8);
        *(uint4*)(sWb + c * LDP + ch * 8) = *(const uint4*)(wbT + c * 64 + ch * 8);
    }
    if (tid < 64) sBias[tid] = biasSum[tid];

    #pragma unroll
    for (int it = 0; it < (RPB * 8) / 256; ++it) {
        int item = it * 256 + tid;
        int r = item >> 3, ch = item & 7;
        long grow = row0 + r;
        uint4 sv = make_uint4(0, 0, 0, 0), ev = make_uint4(0, 0, 0, 0);
        if (grow < NTOT) {
            sv = *(const uint4*)(side_bf + grow * 64 + ch * 8);
            ev = *(const uint4*)(xb + grow * 64 + ch * 8);
        }
        uint4 mv;
        mv.x = f2bf(bf2f(ev.x & 0xffff) * bf2f(sv.x & 0xffff)) |
               ((unsigned int)f2bf(bf2f(ev.x >> 16) * bf2f(sv.x >> 16)) << 16);
        mv.y = f2bf(bf2f(ev.y & 0xffff) * bf2f(sv.y & 0xffff)) |
               ((unsigned int)f2bf(bf2f(ev.y >> 16) * bf2f(sv.y >> 16)) << 16);
        mv.z = f2bf(bf2f(ev.z & 0xffff) * bf2f(sv.z & 0xffff)) |
               ((unsigned int)f2bf(bf2f(ev.z >> 16) * bf2f(sv.z >> 16)) << 16);
        mv.w = f2bf(bf2f(ev.w & 0xffff) * bf2f(sv.w & 0xffff)) |
               ((unsigned int)f2bf(bf2f(ev.w >> 16) * bf2f(sv.w >> 16)) << 16);
        *(uint4*)(sS + r * LDP + ch * 8) = sv;
        *(uint4*)(sM + r * LDP + ch * 8) = mv;
    }
    __syncthreads();

    int wave = tid >> 6, lane = tid & 63;
    int quad = lane >> 4, l16 = lane & 15;

    floatx4 accG[2][4], accB[2][4];
    #pragma unroll
    for (int rt = 0; rt < 2; rt++)
        #pragma unroll
        for (int ct = 0; ct < 4; ct++) {
            accG[rt][ct] = (floatx4){0.f, 0.f, 0.f, 0.f};
            accB[rt][ct] = (floatx4){0.f, 0.f, 0.f, 0.f};
        }

    #pragma unroll
    for (int kc = 0; kc < 64; kc += 32) {
        shortx8 aS[2], aM[2];
        #pragma unroll
        for (int rt = 0; rt < 2; rt++) {
            int r = wave * 32 + rt * 16 + l16;
            aS[rt] = *(const shortx8*)(sS + r * LDP + kc + quad * 8);
            aM[rt] = *(const shortx8*)(sM + r * LDP + kc + quad * 8);
        }
        #pragma unroll
        for (int ct = 0; ct < 4; ct++) {
            int c = ct * 16 + l16;
            shortx8 bG = *(const shortx8*)(sWg + c * LDP + kc + quad * 8);
            shortx8 bB = *(const shortx8*)(sWb + c * LDP + kc + quad * 8);
            #pragma unroll
            for (int rt = 0; rt < 2; rt++) {
                accG[rt][ct] = __builtin_amdgcn_mfma_f32_16x16x32_bf16(aS[rt], bG, accG[rt][ct], 0, 0, 0);
                accB[rt][ct] = __builtin_amdgcn_mfma_f32_16x16x32_bf16(aM[rt], bB, accB[rt][ct], 0, 0, 0);
            }
        }
    }

    // epilogue: bias + leaky relu -> LDS (reuse sM) -> vectorized global store
    __syncthreads();
    #pragma unroll
    for (int rt = 0; rt < 2; rt++)
        #pragma unroll
        for (int ct = 0; ct < 4; ct++) {
            int c = ct * 16 + l16;
            float bs = sBias[c];
            #pragma unroll
            for (int reg = 0; reg < 4; reg++) {
                int r = wave * 32 + rt * 16 + quad * 4 + reg;
                float v = accG[rt][ct][reg] + accB[rt][ct][reg] + bs;
                float o = (v > 0.f) ? v : 0.2f * v;
                sM[r * LDP + c] = f2bf(o);
            }
        }
    __syncthreads();
    #pragma unroll
    for (int it = 0; it < (RPB * 8) / 256; ++it) {
        int item = it * 256 + tid;
        int r = item >> 3, ch = item & 7;
        long grow = row0 + r;
        if (grow < NTOT)
            *(uint4*)(xb + grow * 64 + ch * 8) = *(const uint4*)(sM + r * LDP + ch * 8);
    }
}

// ------------- gather batch rows (optionally L2-normalized) into d_out -------------
__global__ __launch_bounds__(256) void k_gather(const unsigned short* __restrict__ xb,
                                                const int* __restrict__ users,
                                                const int* __restrict__ pos,
                                                const int* __restrict__ neg,
                                                float* __restrict__ out, int colOff, int normalize) {
    int slot = (blockIdx.x * blockDim.x + threadIdx.x) >> 6;
    int lane = threadIdx.x & 63;
    if (slot >= NSLOT) return;
    int row;
    if (slot < BATCHC)          row = users[slot];
    else if (slot < 2 * BATCHC) row = N_USERC + pos[slot - BATCHC];
    else                        row = N_USERC + neg[slot - 2 * BATCHC];
    float v = bf2f(xb[(long)row * 64 + lane]);
    if (normalize) {
        float ss = v * v;
        for (int off = 32; off > 0; off >>= 1) ss += __shfl_xor(ss, off);
        float nrm = fmaxf(sqrtf(ss), 1e-12f);
        v = v / nrm;
    }
    out[(long)slot * 256 + colOff + lane] = v;
}

extern "C" void kernel_launch(void* const* d_in, const int* in_sizes, int n_in,
                              void* d_out, int out_size, void* d_ws, size_t ws_size,
                              hipStream_t stream) {
    const int*   users   = (const int*)d_in[0];
    const int*   pos     = (const int*)d_in[1];
    const int*   neg     = (const int*)d_in[2];
    const int*   adj_row = (const int*)d_in[3];
    const int*   adj_col = (const int*)d_in[4];
    const float* adj_val = (const float*)d_in[5];
    const float* user_emb = (const float*)d_in[6];
    const float* item_emb = (const float*)d_in[7];
    const float* W_gc = (const float*)d_in[8];
    const float* b_gc = (const float*)d_in[9];
    const float* W_bi = (const float*)d_in[10];
    const float* b_bi = (const float*)d_in[11];
    float* out = (float*)d_out;

    // workspace carve-up (~78 MB); ecv aliases pe (pe dead after k_scatterB)
    char* p = (char*)d_ws;
    u64*  pe  = (u64*)p;                        p += (size_t)NNZC * 8;
    u64*  ecv = pe;
    u64*  eb  = (u64*)p;                        p += (size_t)NNZC * 8;
    unsigned short* side_bf = (unsigned short*)p; p += (size_t)NTOT * EMBC * 2;
    unsigned short* xb = (unsigned short*)p;    p += (size_t)NTOT * EMBC * 2;
    int*  rp  = (int*)p;                        p += (size_t)(NTOT + 1) * 4 + 60;
    int*  bcnt = (int*)p;                       p += 1024;
    int*  bbase0 = (int*)p;                     p += 1024;
    int*  gbcur = (int*)p;                      p += 1024;
    unsigned short* wgT = (unsigned short*)p;   p += 3 * 4096 * 2;
    unsigned short* wbT = (unsigned short*)p;   p += 3 * 4096 * 2;
    float* biasSum = (float*)p;                 p += 3 * 64 * 4;

    k_init<<<NB_INIT + 1, 256, 0, stream>>>(
        (const float4*)user_emb, (const float4*)item_emb, (ushort4*)xb,
        W_gc, W_bi, b_gc, b_bi, wgT, wbT, biasSum, bcnt);

    k_packB<<<(NNZC / 4 + 255) / 256, 256, 0, stream>>>(
        (const intx4*)adj_row, (const intx4*)adj_col, (const floatx4*)adj_val, bcnt, pe);
    k_bktscan<<<1, 256, 0, stream>>>(bcnt, bbase0, gbcur);
    k_scatterB<<<(NNZC + 4095) / 4096, 256, 0, stream>>>(pe, gbcur, eb);
    k_csrC<<<NBKT, 256, 0, stream>>>(eb, bbase0, rp, ecv);

    // layer-0 slice of all_embs = raw ego (no normalization)
    k_gather<<<(NSLOT * 64 + 255) / 256, 256, 0, stream>>>(xb, users, pos, neg, out, 0, 0);

    const int NB_LAYER = (NTOT + RPB - 1) / RPB;
    for (int k = 0; k < 3; k++) {
        k_spmm<<<NTOT / 4, 256, 0, stream>>>(rp, (const long*)ecv, xb, side_bf);
        k_layer_mfma<<<NB_LAYER, 256, 0, stream>>>(side_bf, xb,
            wgT + (size_t)k * 4096, wbT + (size_t)k * 4096, biasSum + (size_t)k * 64);
        k_gather<<<(NSLOT * 64 + 255) / 256, 256, 0, stream>>>(xb, users, pos, neg, out, 64 * (k + 1), 1);
    }
}

// Round 11
// 508.326 us; speedup vs baseline: 1.1649x; 1.1081x over previous
//
#include <hip/hip_runtime.h>
#include <hip/hip_bf16.h>

#define N_USERC 50000
#define N_ITEMC 50000
#define NTOT    100000
#define NNZC    3200000
#define EMBC    64
#define BATCHC  4096
#define NSLOT   (3*BATCHC)
#define NBKT    196            // buckets of 512 rows
typedef unsigned long long u64;

typedef __attribute__((ext_vector_type(4))) float floatx4;
typedef __attribute__((ext_vector_type(4))) int   intx4;
typedef __attribute__((ext_vector_type(8))) short shortx8;   // 8 bf16 = 4 VGPRs

__device__ __forceinline__ float bf2f(unsigned short u) {
    return __int_as_float(((int)u) << 16);
}
__device__ __forceinline__ unsigned short f2bf(float f) {
    __hip_bfloat16 h = __float2bfloat16(f);      // RTNE
    return *(unsigned short*)&h;
}
// adj_val in [0,1/32): 15-bit fixed point, step 2^-20 (rel err ~6e-5)
__device__ __forceinline__ unsigned v2fix(float v) {
    int q = (int)(v * 1048576.0f + 0.5f);
    return (unsigned)min(q, 32767);
}

// ---------------- fused init: xb0 = bf16(ego); last block: W^T prep + zero bcnt ----------------
#define NB_INIT (NTOT * EMBC / 4 / 256)   // 6250
__global__ void k_init(const float4* __restrict__ ue, const float4* __restrict__ ie,
                       ushort4* __restrict__ xb0,
                       const float* __restrict__ Wgc, const float* __restrict__ Wbi,
                       const float* __restrict__ bgc, const float* __restrict__ bbi,
                       unsigned short* __restrict__ wgT, unsigned short* __restrict__ wbT,
                       float* __restrict__ biasSum, int* __restrict__ bcnt) {
    int tid = threadIdx.x;
    if (blockIdx.x < NB_INIT) {
        long i = (long)blockIdx.x * 256 + tid;
        const long nu4 = (long)N_USERC * EMBC / 4;
        float4 v = (i < nu4) ? ue[i] : ie[i - nu4];
        ushort4 b; b.x = f2bf(v.x); b.y = f2bf(v.y); b.z = f2bf(v.z); b.w = f2bf(v.w);
        xb0[i] = b;
    } else {
        for (int k = 0; k < 3; k++) {
            for (int i = tid; i < 4096; i += 256) {
                int d = i >> 6, c = i & 63;
                wgT[k * 4096 + c * 64 + d] = f2bf(Wgc[k * 4096 + i]);
                wbT[k * 4096 + c * 64 + d] = f2bf(Wbi[k * 4096 + i]);
            }
            if (tid < 64) biasSum[k * 64 + tid] = bgc[k * 64 + tid] + bbi[k * 64 + tid];
        }
        if (tid < NBKT + 1) bcnt[tid] = 0;
    }
}

// ---------------- pack edges to 8B: row[32..48] | col[15..31] | val15[0..14]; LDS bucket hist ----------------
__global__ __launch_bounds__(256) void k_packB(const intx4* __restrict__ row4, const intx4* __restrict__ col4,
                                               const floatx4* __restrict__ val4, int* __restrict__ bcnt,
                                               u64* __restrict__ pe) {
    __shared__ int bh[NBKT];
    int tid = threadIdx.x;
    for (int i = tid; i < NBKT; i += 256) bh[i] = 0;
    __syncthreads();
    int i = blockIdx.x * 256 + tid;          // group of 4 edges
    if (i < NNZC / 4) {
        intx4 r = __builtin_nontemporal_load(row4 + i);
        intx4 c = __builtin_nontemporal_load(col4 + i);
        floatx4 v = __builtin_nontemporal_load(val4 + i);
        atomicAdd(&bh[r.x >> 9], 1);
        atomicAdd(&bh[r.y >> 9], 1);
        atomicAdd(&bh[r.z >> 9], 1);
        atomicAdd(&bh[r.w >> 9], 1);
        u64 p0 = ((u64)r.x << 32) | ((u64)(unsigned)c.x << 15) | v2fix(v.x);
        u64 p1 = ((u64)r.y << 32) | ((u64)(unsigned)c.y << 15) | v2fix(v.y);
        u64 p2 = ((u64)r.z << 32) | ((u64)(unsigned)c.z << 15) | v2fix(v.z);
        u64 p3 = ((u64)r.w << 32) | ((u64)(unsigned)c.w << 15) | v2fix(v.w);
        u64* dst = pe + (long)i * 4;
        dst[0] = p0; dst[1] = p1; dst[2] = p2; dst[3] = p3;
    }
    __syncthreads();
    for (int b = tid; b < NBKT; b += 256)
        if (bh[b] > 0) atomicAdd(&bcnt[b], bh[b]);
}

// ---------------- scan 196 bucket counts -> bases; init cursors ----------------
__global__ void k_bktscan(const int* __restrict__ bcnt, int* __restrict__ bbase0,
                          int* __restrict__ gbcur) {
    __shared__ int sm[256];
    int t = threadIdx.x;
    int v = (t < NBKT) ? bcnt[t] : 0;
    sm[t] = v;
    __syncthreads();
    for (int off = 1; off < 256; off <<= 1) {
        int u = (t >= off) ? sm[t - off] : 0;
        __syncthreads();
        sm[t] += u;
        __syncthreads();
    }
    if (t < NBKT) {
        int base = sm[t] - v;   // exclusive
        bbase0[t] = base;
        gbcur[t] = base;
    }
    if (t == 0) bbase0[NBKT] = NNZC;
}

// ---------------- bucket partition: block-bulk reservation ----------------
__global__ __launch_bounds__(256) void k_scatterB(const u64* __restrict__ pe, int* __restrict__ gbcur,
                                                  u64* __restrict__ eb) {
    __shared__ int bh[NBKT], bbase[NBKT], bcur[NBKT];
    int tid = threadIdx.x;
    for (int i = tid; i < NBKT; i += 256) { bh[i] = 0; bcur[i] = 0; }
    __syncthreads();
    long base = (long)blockIdx.x * 4096;
    u64 e[16]; int bk[16];
    #pragma unroll
    for (int i = 0; i < 16; i++) {
        long idx = base + i * 256 + tid;
        if (idx < NNZC) {
            e[i] = __builtin_nontemporal_load(pe + idx);
            bk[i] = (int)(e[i] >> 41);      // row >> 9
            atomicAdd(&bh[bk[i]], 1);
        } else bk[i] = -1;
    }
    __syncthreads();
    for (int i = tid; i < NBKT; i += 256)
        if (bh[i] > 0) bbase[i] = atomicAdd(&gbcur[i], bh[i]);
    __syncthreads();
    #pragma unroll
    for (int i = 0; i < 16; i++) {
        if (bk[i] >= 0) {
            int p = bbase[bk[i]] + atomicAdd(&bcur[bk[i]], 1);
            eb[p] = e[i];
        }
    }
}

// ---------------- bucket -> row-CSR + rp build: one block per bucket; ecv is u32 ----------------
__global__ __launch_bounds__(256) void k_csrC(const u64* __restrict__ eb, const int* __restrict__ bbase0,
                                              int* __restrict__ rp, unsigned* __restrict__ ecv) {
    __shared__ int lhist[512];
    __shared__ int lcur[512];
    __shared__ int sm[256];
    int b = blockIdx.x;
    int tid = threadIdx.x;
    int row0 = b << 9;
    lhist[tid] = 0; lhist[tid + 256] = 0;
    __syncthreads();
    int start = bbase0[b];
    int end = bbase0[b + 1];
    for (int e = start + tid; e < end; e += 256) {
        u64 w = eb[e];
        int rl = (int)((w >> 32) & 0x1FFFF) - row0;
        atomicAdd(&lhist[rl], 1);
    }
    __syncthreads();
    int h0 = lhist[2 * tid], h1 = lhist[2 * tid + 1];
    int pair = h0 + h1;
    sm[tid] = pair;
    __syncthreads();
    for (int off = 1; off < 256; off <<= 1) {
        int u = (tid >= off) ? sm[tid - off] : 0;
        __syncthreads();
        sm[tid] += u;
        __syncthreads();
    }
    int pairExcl = sm[tid] - pair;
    int e0 = start + pairExcl;
    int e1 = e0 + h0;
    lcur[2 * tid] = e0;
    lcur[2 * tid + 1] = e1;
    int rg0 = row0 + 2 * tid, rg1 = rg0 + 1;
    if (rg0 < NTOT) rp[rg0] = e0;
    if (rg1 < NTOT) rp[rg1] = e1;
    if (b == NBKT - 1 && tid == 0) rp[NTOT] = NNZC;
    __syncthreads();
    for (int e = start + tid; e < end; e += 256) {
        u64 w = eb[e];
        int rl = (int)((w >> 32) & 0x1FFFF) - row0;
        int p = atomicAdd(&lcur[rl], 1);
        ecv[p] = (unsigned)(w & 0xFFFFFFFFu);   // col<<15 | val15
    }
}

// ---------------- SpMM: one wave per row, 16 edges/step (16 lanes per edge); u32 edges ----------------
__global__ __launch_bounds__(256) void k_spmm(const int* __restrict__ rp, const unsigned* __restrict__ ecv,
                                              const unsigned short* __restrict__ xb,
                                              unsigned short* __restrict__ side_bf) {
    int r = (blockIdx.x * blockDim.x + threadIdx.x) >> 6;
    int lane = threadIdx.x & 63;
    if (r >= NTOT) return;
    int q = lane >> 4;
    int t4 = (lane & 15) * 4;
    int s = rp[r], e = rp[r + 1];
    float a0 = 0.f, a1 = 0.f, a2 = 0.f, a3 = 0.f;
    for (int j = s; j < e; j += 16) {
        unsigned pk[4];
        bool vm[4];
        #pragma unroll
        for (int u = 0; u < 4; ++u) {
            int je = j + u * 4 + q;
            vm[u] = (je < e);
            pk[u] = __builtin_nontemporal_load(ecv + (vm[u] ? je : s));
        }
        ushort4 xv[4];
        #pragma unroll
        for (int u = 0; u < 4; ++u)
            xv[u] = *(const ushort4*)(xb + (long)(pk[u] >> 15) * EMBC + t4);
        #pragma unroll
        for (int u = 0; u < 4; ++u) {
            float w = vm[u] ? (float)(pk[u] & 0x7FFF) * (1.0f / 1048576.0f) : 0.f;
            a0 += w * bf2f(xv[u].x);
            a1 += w * bf2f(xv[u].y);
            a2 += w * bf2f(xv[u].z);
            a3 += w * bf2f(xv[u].w);
        }
    }
    a0 += __shfl_xor(a0, 16); a1 += __shfl_xor(a1, 16); a2 += __shfl_xor(a2, 16); a3 += __shfl_xor(a3, 16);
    a0 += __shfl_xor(a0, 32); a1 += __shfl_xor(a1, 32); a2 += __shfl_xor(a2, 32); a3 += __shfl_xor(a3, 32);
    if (lane < 16) {
        ushort4 o; o.x = f2bf(a0); o.y = f2bf(a1); o.z = f2bf(a2); o.w = f2bf(a3);
        *(ushort4*)(side_bf + (long)r * EMBC + t4) = o;
    }
}

// ------------- MFMA layer (R8 epilogue): xb_in -> xb_out -------------
#define RPB 128
#define LDP 72
__global__ __launch_bounds__(256) void k_layer_mfma(
    const unsigned short* __restrict__ side_bf, const unsigned short* __restrict__ xb_in,
    unsigned short* __restrict__ xb_out,
    const unsigned short* __restrict__ wgT, const unsigned short* __restrict__ wbT,
    const float* __restrict__ biasSum)
{
    __shared__ unsigned short sS[RPB * LDP];
    __shared__ unsigned short sM[RPB * LDP];
    __shared__ unsigned short sWg[64 * LDP];
    __shared__ unsigned short sWb[64 * LDP];
    __shared__ float sBias[64];

    int tid = threadIdx.x;
    int row0 = blockIdx.x * RPB;

    #pragma unroll
    for (int it = 0; it < 2; ++it) {
        int item = it * 256 + tid;          // 0..511
        int c = item >> 3, ch = item & 7;
        *(uint4*)(sWg + c * LDP + ch * 8) = *(const uint4*)(wgT + c * 64 + ch * 8);
        *(uint4*)(sWb + c * LDP + ch * 8) = *(const uint4*)(wbT + c * 64 + ch * 8);
    }
    if (tid < 64) sBias[tid] = biasSum[tid];

    #pragma unroll
    for (int it = 0; it < (RPB * 8) / 256; ++it) {
        int item = it * 256 + tid;
        int r = item >> 3, ch = item & 7;
        long grow = row0 + r;
        uint4 sv = make_uint4(0, 0, 0, 0), ev = make_uint4(0, 0, 0, 0);
        if (grow < NTOT) {
            sv = *(const uint4*)(side_bf + grow * 64 + ch * 8);
            ev = *(const uint4*)(xb_in + grow * 64 + ch * 8);
        }
        uint4 mv;
        mv.x = f2bf(bf2f(ev.x & 0xffff) * bf2f(sv.x & 0xffff)) |
               ((unsigned int)f2bf(bf2f(ev.x >> 16) * bf2f(sv.x >> 16)) << 16);
        mv.y = f2bf(bf2f(ev.y & 0xffff) * bf2f(sv.y & 0xffff)) |
               ((unsigned int)f2bf(bf2f(ev.y >> 16) * bf2f(sv.y >> 16)) << 16);
        mv.z = f2bf(bf2f(ev.z & 0xffff) * bf2f(sv.z & 0xffff)) |
               ((unsigned int)f2bf(bf2f(ev.z >> 16) * bf2f(sv.z >> 16)) << 16);
        mv.w = f2bf(bf2f(ev.w & 0xffff) * bf2f(sv.w & 0xffff)) |
               ((unsigned int)f2bf(bf2f(ev.w >> 16) * bf2f(sv.w >> 16)) << 16);
        *(uint4*)(sS + r * LDP + ch * 8) = sv;
        *(uint4*)(sM + r * LDP + ch * 8) = mv;
    }
    __syncthreads();

    int wave = tid >> 6, lane = tid & 63;
    int quad = lane >> 4, l16 = lane & 15;

    floatx4 accG[2][4], accB[2][4];
    #pragma unroll
    for (int rt = 0; rt < 2; rt++)
        #pragma unroll
        for (int ct = 0; ct < 4; ct++) {
            accG[rt][ct] = (floatx4){0.f, 0.f, 0.f, 0.f};
            accB[rt][ct] = (floatx4){0.f, 0.f, 0.f, 0.f};
        }

    #pragma unroll
    for (int kc = 0; kc < 64; kc += 32) {
        shortx8 aS[2], aM[2];
        #pragma unroll
        for (int rt = 0; rt < 2; rt++) {
            int r = wave * 32 + rt * 16 + l16;
            aS[rt] = *(const shortx8*)(sS + r * LDP + kc + quad * 8);
            aM[rt] = *(const shortx8*)(sM + r * LDP + kc + quad * 8);
        }
        #pragma unroll
        for (int ct = 0; ct < 4; ct++) {
            int c = ct * 16 + l16;
            shortx8 bG = *(const shortx8*)(sWg + c * LDP + kc + quad * 8);
            shortx8 bB = *(const shortx8*)(sWb + c * LDP + kc + quad * 8);
            #pragma unroll
            for (int rt = 0; rt < 2; rt++) {
                accG[rt][ct] = __builtin_amdgcn_mfma_f32_16x16x32_bf16(aS[rt], bG, accG[rt][ct], 0, 0, 0);
                accB[rt][ct] = __builtin_amdgcn_mfma_f32_16x16x32_bf16(aM[rt], bB, accB[rt][ct], 0, 0, 0);
            }
        }
    }

    #pragma unroll
    for (int rt = 0; rt < 2; rt++)
        #pragma unroll
        for (int ct = 0; ct < 4; ct++) {
            int c = ct * 16 + l16;
            float bs = sBias[c];
            #pragma unroll
            for (int reg = 0; reg < 4; reg++) {
                int r = wave * 32 + rt * 16 + quad * 4 + reg;
                long grow = row0 + r;
                if (grow < NTOT) {
                    float v = accG[rt][ct][reg] + accB[rt][ct][reg] + bs;
                    float o = (v > 0.f) ? v : 0.2f * v;
                    xb_out[grow * 64 + c] = f2bf(o);
                }
            }
        }
}

// ------------- single fused gather: all 4 column-blocks (layer 0 raw, 1-3 normalized) -------------
__global__ __launch_bounds__(256) void k_gatherAll(
    const unsigned short* __restrict__ xb0, const unsigned short* __restrict__ xb1,
    const unsigned short* __restrict__ xb2, const unsigned short* __restrict__ xb3,
    const int* __restrict__ users, const int* __restrict__ pos, const int* __restrict__ neg,
    float* __restrict__ out) {
    int gw = (blockIdx.x * blockDim.x + threadIdx.x) >> 6;   // slot*4 + layer
    int lane = threadIdx.x & 63;
    int slot = gw >> 2, layer = gw & 3;
    if (slot >= NSLOT) return;
    int row;
    if (slot < BATCHC)          row = users[slot];
    else if (slot < 2 * BATCHC) row = N_USERC + pos[slot - BATCHC];
    else                        row = N_USERC + neg[slot - 2 * BATCHC];
    const unsigned short* src = (layer == 0) ? xb0 : (layer == 1) ? xb1 : (layer == 2) ? xb2 : xb3;
    float v = bf2f(src[(long)row * 64 + lane]);
    if (layer != 0) {
        float ss = v * v;
        for (int off = 32; off > 0; off >>= 1) ss += __shfl_xor(ss, off);
        float nrm = fmaxf(sqrtf(ss), 1e-12f);
        v = v / nrm;
    }
    out[(long)slot * 256 + layer * 64 + lane] = v;
}

extern "C" void kernel_launch(void* const* d_in, const int* in_sizes, int n_in,
                              void* d_out, int out_size, void* d_ws, size_t ws_size,
                              hipStream_t stream) {
    const int*   users   = (const int*)d_in[0];
    const int*   pos     = (const int*)d_in[1];
    const int*   neg     = (const int*)d_in[2];
    const int*   adj_row = (const int*)d_in[3];
    const int*   adj_col = (const int*)d_in[4];
    const float* adj_val = (const float*)d_in[5];
    const float* user_emb = (const float*)d_in[6];
    const float* item_emb = (const float*)d_in[7];
    const float* W_gc = (const float*)d_in[8];
    const float* b_gc = (const float*)d_in[9];
    const float* W_bi = (const float*)d_in[10];
    const float* b_bi = (const float*)d_in[11];
    float* out = (float*)d_out;

    // workspace (~91 MB). Aliasing: ecv(u32,12.8MB) overlays pe (dead after scatterB);
    // xb2/xb3 overlay eb (dead after csrC).
    char* p = (char*)d_ws;
    u64*  pe  = (u64*)p;                        p += (size_t)NNZC * 8;     // 25.6 MB
    unsigned* ecv = (unsigned*)pe;
    u64*  eb  = (u64*)p;                        p += (size_t)NNZC * 8;     // 25.6 MB
    unsigned short* xb2 = (unsigned short*)eb;
    unsigned short* xb3 = (unsigned short*)((char*)eb + (size_t)NTOT * EMBC * 2);
    unsigned short* side_bf = (unsigned short*)p; p += (size_t)NTOT * EMBC * 2;
    unsigned short* xb0 = (unsigned short*)p;   p += (size_t)NTOT * EMBC * 2;
    unsigned short* xb1 = (unsigned short*)p;   p += (size_t)NTOT * EMBC * 2;
    int*  rp  = (int*)p;                        p += (size_t)(NTOT + 1) * 4 + 60;
    int*  bcnt = (int*)p;                       p += 1024;
    int*  bbase0 = (int*)p;                     p += 1024;
    int*  gbcur = (int*)p;                      p += 1024;
    unsigned short* wgT = (unsigned short*)p;   p += 3 * 4096 * 2;
    unsigned short* wbT = (unsigned short*)p;   p += 3 * 4096 * 2;
    float* biasSum = (float*)p;                 p += 3 * 64 * 4;

    k_init<<<NB_INIT + 1, 256, 0, stream>>>(
        (const float4*)user_emb, (const float4*)item_emb, (ushort4*)xb0,
        W_gc, W_bi, b_gc, b_bi, wgT, wbT, biasSum, bcnt);

    k_packB<<<(NNZC / 4 + 255) / 256, 256, 0, stream>>>(
        (const intx4*)adj_row, (const intx4*)adj_col, (const floatx4*)adj_val, bcnt, pe);
    k_bktscan<<<1, 256, 0, stream>>>(bcnt, bbase0, gbcur);
    k_scatterB<<<(NNZC + 4095) / 4096, 256, 0, stream>>>(pe, gbcur, eb);
    k_csrC<<<NBKT, 256, 0, stream>>>(eb, bbase0, rp, ecv);

    unsigned short* xbs[4] = {xb0, xb1, xb2, xb3};
    const int NB_LAYER = (NTOT + RPB - 1) / RPB;
    for (int k = 0; k < 3; k++) {
        k_spmm<<<NTOT / 4, 256, 0, stream>>>(rp, ecv, xbs[k], side_bf);
        k_layer_mfma<<<NB_LAYER, 256, 0, stream>>>(side_bf, xbs[k], xbs[k + 1],
            wgT + (size_t)k * 4096, wbT + (size_t)k * 4096, biasSum + (size_t)k * 64);
    }
    k_gatherAll<<<(NSLOT * 4) / 4, 256, 0, stream>>>(xb0, xb1, xb2, xb3, users, pos, neg, out);
}

// Round 12
// 505.691 us; speedup vs baseline: 1.1710x; 1.0052x over previous
//
#include <hip/hip_runtime.h>
#include <hip/hip_bf16.h>

#define N_USERC 50000
#define N_ITEMC 50000
#define NTOT    100000
#define NNZC    3200000
#define NGRP    (NNZC/4)       // 800000 groups of 4 edges
#define EMBC    64
#define BATCHC  4096
#define NSLOT   (3*BATCHC)
#define NBKT    196            // buckets of 512 rows
typedef unsigned long long u64;

typedef __attribute__((ext_vector_type(4))) float floatx4;
typedef __attribute__((ext_vector_type(4))) int   intx4;
typedef __attribute__((ext_vector_type(8))) short shortx8;   // 8 bf16 = 4 VGPRs

__device__ __forceinline__ float bf2f(unsigned short u) {
    return __int_as_float(((int)u) << 16);
}
__device__ __forceinline__ unsigned short f2bf(float f) {
    __hip_bfloat16 h = __float2bfloat16(f);      // RTNE
    return *(unsigned short*)&h;
}
// adj_val in [0,1/32): 15-bit fixed point, step 2^-20 (rel err ~6e-5)
__device__ __forceinline__ unsigned v2fix(float v) {
    int q = (int)(v * 1048576.0f + 0.5f);
    return (unsigned)min(q, 32767);
}

// ---------------- fused init: xb0 = bf16(ego); last block: W^T prep + zero bcnt ----------------
#define NB_INIT (NTOT * EMBC / 4 / 256)   // 6250
__global__ void k_init(const float4* __restrict__ ue, const float4* __restrict__ ie,
                       ushort4* __restrict__ xb0,
                       const float* __restrict__ Wgc, const float* __restrict__ Wbi,
                       const float* __restrict__ bgc, const float* __restrict__ bbi,
                       unsigned short* __restrict__ wgT, unsigned short* __restrict__ wbT,
                       float* __restrict__ biasSum, int* __restrict__ bcnt) {
    int tid = threadIdx.x;
    if (blockIdx.x < NB_INIT) {
        long i = (long)blockIdx.x * 256 + tid;
        const long nu4 = (long)N_USERC * EMBC / 4;
        float4 v = (i < nu4) ? ue[i] : ie[i - nu4];
        ushort4 b; b.x = f2bf(v.x); b.y = f2bf(v.y); b.z = f2bf(v.z); b.w = f2bf(v.w);
        xb0[i] = b;
    } else {
        for (int k = 0; k < 3; k++) {
            for (int i = tid; i < 4096; i += 256) {
                int d = i >> 6, c = i & 63;
                wgT[k * 4096 + c * 64 + d] = f2bf(Wgc[k * 4096 + i]);
                wbT[k * 4096 + c * 64 + d] = f2bf(Wbi[k * 4096 + i]);
            }
            if (tid < 64) biasSum[k * 64 + tid] = bgc[k * 64 + tid] + bbi[k * 64 + tid];
        }
        if (tid < NBKT + 1) bcnt[tid] = 0;
    }
}

// ---------------- count: LDS bucket histogram from adj_row only ----------------
__global__ __launch_bounds__(256) void k_count(const intx4* __restrict__ row4, int* __restrict__ bcnt) {
    __shared__ int bh[NBKT];
    int tid = threadIdx.x;
    for (int i = tid; i < NBKT; i += 256) bh[i] = 0;
    __syncthreads();
    int i = blockIdx.x * 256 + tid;
    if (i < NGRP) {
        intx4 r = __builtin_nontemporal_load(row4 + i);
        atomicAdd(&bh[r.x >> 9], 1);
        atomicAdd(&bh[r.y >> 9], 1);
        atomicAdd(&bh[r.z >> 9], 1);
        atomicAdd(&bh[r.w >> 9], 1);
    }
    __syncthreads();
    for (int b = tid; b < NBKT; b += 256)
        if (bh[b] > 0) atomicAdd(&bcnt[b], bh[b]);
}

// ---------------- scan 196 bucket counts -> bases; init cursors ----------------
__global__ void k_bktscan(const int* __restrict__ bcnt, int* __restrict__ bbase0,
                          int* __restrict__ gbcur) {
    __shared__ int sm[256];
    int t = threadIdx.x;
    int v = (t < NBKT) ? bcnt[t] : 0;
    sm[t] = v;
    __syncthreads();
    for (int off = 1; off < 256; off <<= 1) {
        int u = (t >= off) ? sm[t - off] : 0;
        __syncthreads();
        sm[t] += u;
        __syncthreads();
    }
    if (t < NBKT) {
        int base = sm[t] - v;   // exclusive
        bbase0[t] = base;
        gbcur[t] = base;
    }
    if (t == 0) bbase0[NBKT] = NNZC;
}

// ---------------- pack + bucket partition in one pass: block-bulk reservation ----------------
__global__ __launch_bounds__(256) void k_scatterP(const intx4* __restrict__ row4, const intx4* __restrict__ col4,
                                                  const floatx4* __restrict__ val4, int* __restrict__ gbcur,
                                                  u64* __restrict__ eb) {
    __shared__ int bh[NBKT], bbase[NBKT], bcur[NBKT];
    int tid = threadIdx.x;
    for (int i = tid; i < NBKT; i += 256) { bh[i] = 0; bcur[i] = 0; }
    __syncthreads();
    long gbase = (long)blockIdx.x * 1024;     // 1024 groups = 4096 edges per block
    u64 e[16]; int bk[16];
    #pragma unroll
    for (int it = 0; it < 4; ++it) {
        long g = gbase + it * 256 + tid;
        if (g < NGRP) {
            intx4 r = __builtin_nontemporal_load(row4 + g);
            intx4 c = __builtin_nontemporal_load(col4 + g);
            floatx4 v = __builtin_nontemporal_load(val4 + g);
            e[it*4+0] = ((u64)r.x << 32) | ((u64)(unsigned)c.x << 15) | v2fix(v.x); bk[it*4+0] = r.x >> 9;
            e[it*4+1] = ((u64)r.y << 32) | ((u64)(unsigned)c.y << 15) | v2fix(v.y); bk[it*4+1] = r.y >> 9;
            e[it*4+2] = ((u64)r.z << 32) | ((u64)(unsigned)c.z << 15) | v2fix(v.z); bk[it*4+2] = r.z >> 9;
            e[it*4+3] = ((u64)r.w << 32) | ((u64)(unsigned)c.w << 15) | v2fix(v.w); bk[it*4+3] = r.w >> 9;
            atomicAdd(&bh[bk[it*4+0]], 1);
            atomicAdd(&bh[bk[it*4+1]], 1);
            atomicAdd(&bh[bk[it*4+2]], 1);
            atomicAdd(&bh[bk[it*4+3]], 1);
        } else {
            bk[it*4+0] = bk[it*4+1] = bk[it*4+2] = bk[it*4+3] = -1;
        }
    }
    __syncthreads();
    for (int i = tid; i < NBKT; i += 256)
        if (bh[i] > 0) bbase[i] = atomicAdd(&gbcur[i], bh[i]);
    __syncthreads();
    #pragma unroll
    for (int i = 0; i < 16; i++) {
        if (bk[i] >= 0) {
            int p = bbase[bk[i]] + atomicAdd(&bcur[bk[i]], 1);
            eb[p] = e[i];
        }
    }
}

// ---------------- bucket -> row-CSR + rp build: one block per bucket; ecv is u32 ----------------
__global__ __launch_bounds__(256) void k_csrC(const u64* __restrict__ eb, const int* __restrict__ bbase0,
                                              int* __restrict__ rp, unsigned* __restrict__ ecv) {
    __shared__ int lhist[512];
    __shared__ int lcur[512];
    __shared__ int sm[256];
    int b = blockIdx.x;
    int tid = threadIdx.x;
    int row0 = b << 9;
    lhist[tid] = 0; lhist[tid + 256] = 0;
    __syncthreads();
    int start = bbase0[b];
    int end = bbase0[b + 1];
    for (int e = start + tid; e < end; e += 256) {
        u64 w = eb[e];
        int rl = (int)((w >> 32) & 0x1FFFF) - row0;
        atomicAdd(&lhist[rl], 1);
    }
    __syncthreads();
    int h0 = lhist[2 * tid], h1 = lhist[2 * tid + 1];
    int pair = h0 + h1;
    sm[tid] = pair;
    __syncthreads();
    for (int off = 1; off < 256; off <<= 1) {
        int u = (tid >= off) ? sm[tid - off] : 0;
        __syncthreads();
        sm[tid] += u;
        __syncthreads();
    }
    int pairExcl = sm[tid] - pair;
    int e0 = start + pairExcl;
    int e1 = e0 + h0;
    lcur[2 * tid] = e0;
    lcur[2 * tid + 1] = e1;
    int rg0 = row0 + 2 * tid, rg1 = rg0 + 1;
    if (rg0 < NTOT) rp[rg0] = e0;
    if (rg1 < NTOT) rp[rg1] = e1;
    if (b == NBKT - 1 && tid == 0) rp[NTOT] = NNZC;
    __syncthreads();
    for (int e = start + tid; e < end; e += 256) {
        u64 w = eb[e];
        int rl = (int)((w >> 32) & 0x1FFFF) - row0;
        int p = atomicAdd(&lcur[rl], 1);
        ecv[p] = (unsigned)(w & 0xFFFFFFFFu);   // col<<15 | val15
    }
}

// ---------------- SpMM: one wave per row, 16 edges/step (16 lanes per edge); u32 edges ----------------
__global__ __launch_bounds__(256) void k_spmm(const int* __restrict__ rp, const unsigned* __restrict__ ecv,
                                              const unsigned short* __restrict__ xb,
                                              unsigned short* __restrict__ side_bf) {
    int r = (blockIdx.x * blockDim.x + threadIdx.x) >> 6;
    int lane = threadIdx.x & 63;
    if (r >= NTOT) return;
    int q = lane >> 4;
    int t4 = (lane & 15) * 4;
    int s = rp[r], e = rp[r + 1];
    float a0 = 0.f, a1 = 0.f, a2 = 0.f, a3 = 0.f;
    for (int j = s; j < e; j += 16) {
        unsigned pk[4];
        bool vm[4];
        #pragma unroll
        for (int u = 0; u < 4; ++u) {
            int je = j + u * 4 + q;
            vm[u] = (je < e);
            pk[u] = __builtin_nontemporal_load(ecv + (vm[u] ? je : s));
        }
        ushort4 xv[4];
        #pragma unroll
        for (int u = 0; u < 4; ++u)
            xv[u] = *(const ushort4*)(xb + (long)(pk[u] >> 15) * EMBC + t4);
        #pragma unroll
        for (int u = 0; u < 4; ++u) {
            float w = vm[u] ? (float)(pk[u] & 0x7FFF) * (1.0f / 1048576.0f) : 0.f;
            a0 += w * bf2f(xv[u].x);
            a1 += w * bf2f(xv[u].y);
            a2 += w * bf2f(xv[u].z);
            a3 += w * bf2f(xv[u].w);
        }
    }
    a0 += __shfl_xor(a0, 16); a1 += __shfl_xor(a1, 16); a2 += __shfl_xor(a2, 16); a3 += __shfl_xor(a3, 16);
    a0 += __shfl_xor(a0, 32); a1 += __shfl_xor(a1, 32); a2 += __shfl_xor(a2, 32); a3 += __shfl_xor(a3, 32);
    if (lane < 16) {
        ushort4 o; o.x = f2bf(a0); o.y = f2bf(a1); o.z = f2bf(a2); o.w = f2bf(a3);
        *(ushort4*)(side_bf + (long)r * EMBC + t4) = o;
    }
}

// ------------- MFMA layer: xb_in -> xb_out -------------
#define RPB 128
#define LDP 72
__global__ __launch_bounds__(256) void k_layer_mfma(
    const unsigned short* __restrict__ side_bf, const unsigned short* __restrict__ xb_in,
    unsigned short* __restrict__ xb_out,
    const unsigned short* __restrict__ wgT, const unsigned short* __restrict__ wbT,
    const float* __restrict__ biasSum)
{
    __shared__ unsigned short sS[RPB * LDP];
    __shared__ unsigned short sM[RPB * LDP];
    __shared__ unsigned short sWg[64 * LDP];
    __shared__ unsigned short sWb[64 * LDP];
    __shared__ float sBias[64];

    int tid = threadIdx.x;
    int row0 = blockIdx.x * RPB;

    #pragma unroll
    for (int it = 0; it < 2; ++it) {
        int item = it * 256 + tid;          // 0..511
        int c = item >> 3, ch = item & 7;
        *(uint4*)(sWg + c * LDP + ch * 8) = *(const uint4*)(wgT + c * 64 + ch * 8);
        *(uint4*)(sWb + c * LDP + ch * 8) = *(const uint4*)(wbT + c * 64 + ch * 8);
    }
    if (tid < 64) sBias[tid] = biasSum[tid];

    #pragma unroll
    for (int it = 0; it < (RPB * 8) / 256; ++it) {
        int item = it * 256 + tid;
        int r = item >> 3, ch = item & 7;
        long grow = row0 + r;
        uint4 sv = make_uint4(0, 0, 0, 0), ev = make_uint4(0, 0, 0, 0);
        if (grow < NTOT) {
            sv = *(const uint4*)(side_bf + grow * 64 + ch * 8);
            ev = *(const uint4*)(xb_in + grow * 64 + ch * 8);
        }
        uint4 mv;
        mv.x = f2bf(bf2f(ev.x & 0xffff) * bf2f(sv.x & 0xffff)) |
               ((unsigned int)f2bf(bf2f(ev.x >> 16) * bf2f(sv.x >> 16)) << 16);
        mv.y = f2bf(bf2f(ev.y & 0xffff) * bf2f(sv.y & 0xffff)) |
               ((unsigned int)f2bf(bf2f(ev.y >> 16) * bf2f(sv.y >> 16)) << 16);
        mv.z = f2bf(bf2f(ev.z & 0xffff) * bf2f(sv.z & 0xffff)) |
               ((unsigned int)f2bf(bf2f(ev.z >> 16) * bf2f(sv.z >> 16)) << 16);
        mv.w = f2bf(bf2f(ev.w & 0xffff) * bf2f(sv.w & 0xffff)) |
               ((unsigned int)f2bf(bf2f(ev.w >> 16) * bf2f(sv.w >> 16)) << 16);
        *(uint4*)(sS + r * LDP + ch * 8) = sv;
        *(uint4*)(sM + r * LDP + ch * 8) = mv;
    }
    __syncthreads();

    int wave = tid >> 6, lane = tid & 63;
    int quad = lane >> 4, l16 = lane & 15;

    floatx4 accG[2][4], accB[2][4];
    #pragma unroll
    for (int rt = 0; rt < 2; rt++)
        #pragma unroll
        for (int ct = 0; ct < 4; ct++) {
            accG[rt][ct] = (floatx4){0.f, 0.f, 0.f, 0.f};
            accB[rt][ct] = (floatx4){0.f, 0.f, 0.f, 0.f};
        }

    #pragma unroll
    for (int kc = 0; kc < 64; kc += 32) {
        shortx8 aS[2], aM[2];
        #pragma unroll
        for (int rt = 0; rt < 2; rt++) {
            int r = wave * 32 + rt * 16 + l16;
            aS[rt] = *(const shortx8*)(sS + r * LDP + kc + quad * 8);
            aM[rt] = *(const shortx8*)(sM + r * LDP + kc + quad * 8);
        }
        #pragma unroll
        for (int ct = 0; ct < 4; ct++) {
            int c = ct * 16 + l16;
            shortx8 bG = *(const shortx8*)(sWg + c * LDP + kc + quad * 8);
            shortx8 bB = *(const shortx8*)(sWb + c * LDP + kc + quad * 8);
            #pragma unroll
            for (int rt = 0; rt < 2; rt++) {
                accG[rt][ct] = __builtin_amdgcn_mfma_f32_16x16x32_bf16(aS[rt], bG, accG[rt][ct], 0, 0, 0);
                accB[rt][ct] = __builtin_amdgcn_mfma_f32_16x16x32_bf16(aM[rt], bB, accB[rt][ct], 0, 0, 0);
            }
        }
    }

    #pragma unroll
    for (int rt = 0; rt < 2; rt++)
        #pragma unroll
        for (int ct = 0; ct < 4; ct++) {
            int c = ct * 16 + l16;
            float bs = sBias[c];
            #pragma unroll
            for (int reg = 0; reg < 4; reg++) {
                int r = wave * 32 + rt * 16 + quad * 4 + reg;
                long grow = row0 + r;
                if (grow < NTOT) {
                    float v = accG[rt][ct][reg] + accB[rt][ct][reg] + bs;
                    float o = (v > 0.f) ? v : 0.2f * v;
                    xb_out[grow * 64 + c] = f2bf(o);
                }
            }
        }
}

// ------------- single fused gather: all 4 column-blocks (layer 0 raw, 1-3 normalized) -------------
__global__ __launch_bounds__(256) void k_gatherAll(
    const unsigned short* __restrict__ xb0, const unsigned short* __restrict__ xb1,
    const unsigned short* __restrict__ xb2, const unsigned short* __restrict__ xb3,
    const int* __restrict__ users, const int* __restrict__ pos, const int* __restrict__ neg,
    float* __restrict__ out) {
    int gw = (blockIdx.x * blockDim.x + threadIdx.x) >> 6;   // slot*4 + layer
    int lane = threadIdx.x & 63;
    int slot = gw >> 2, layer = gw & 3;
    if (slot >= NSLOT) return;
    int row;
    if (slot < BATCHC)          row = users[slot];
    else if (slot < 2 * BATCHC) row = N_USERC + pos[slot - BATCHC];
    else                        row = N_USERC + neg[slot - 2 * BATCHC];
    const unsigned short* src = (layer == 0) ? xb0 : (layer == 1) ? xb1 : (layer == 2) ? xb2 : xb3;
    float v = bf2f(src[(long)row * 64 + lane]);
    if (layer != 0) {
        float ss = v * v;
        for (int off = 32; off > 0; off >>= 1) ss += __shfl_xor(ss, off);
        float nrm = fmaxf(sqrtf(ss), 1e-12f);
        v = v / nrm;
    }
    out[(long)slot * 256 + layer * 64 + lane] = v;
}

extern "C" void kernel_launch(void* const* d_in, const int* in_sizes, int n_in,
                              void* d_out, int out_size, void* d_ws, size_t ws_size,
                              hipStream_t stream) {
    const int*   users   = (const int*)d_in[0];
    const int*   pos     = (const int*)d_in[1];
    const int*   neg     = (const int*)d_in[2];
    const int*   adj_row = (const int*)d_in[3];
    const int*   adj_col = (const int*)d_in[4];
    const float* adj_val = (const float*)d_in[5];
    const float* user_emb = (const float*)d_in[6];
    const float* item_emb = (const float*)d_in[7];
    const float* W_gc = (const float*)d_in[8];
    const float* b_gc = (const float*)d_in[9];
    const float* W_bi = (const float*)d_in[10];
    const float* b_bi = (const float*)d_in[11];
    float* out = (float*)d_out;

    // workspace (~66 MB). Aliasing: xb2/xb3 overlay eb (eb dead after csrC).
    char* p = (char*)d_ws;
    unsigned* ecv = (unsigned*)p;               p += (size_t)NNZC * 4;     // 12.8 MB
    u64*  eb  = (u64*)p;                        p += (size_t)NNZC * 8;     // 25.6 MB
    unsigned short* xb2 = (unsigned short*)eb;
    unsigned short* xb3 = (unsigned short*)((char*)eb + (size_t)NTOT * EMBC * 2);
    unsigned short* side_bf = (unsigned short*)p; p += (size_t)NTOT * EMBC * 2;
    unsigned short* xb0 = (unsigned short*)p;   p += (size_t)NTOT * EMBC * 2;
    unsigned short* xb1 = (unsigned short*)p;   p += (size_t)NTOT * EMBC * 2;
    int*  rp  = (int*)p;                        p += (size_t)(NTOT + 1) * 4 + 60;
    int*  bcnt = (int*)p;                       p += 1024;
    int*  bbase0 = (int*)p;                     p += 1024;
    int*  gbcur = (int*)p;                      p += 1024;
    unsigned short* wgT = (unsigned short*)p;   p += 3 * 4096 * 2;
    unsigned short* wbT = (unsigned short*)p;   p += 3 * 4096 * 2;
    float* biasSum = (float*)p;                 p += 3 * 64 * 4;

    k_init<<<NB_INIT + 1, 256, 0, stream>>>(
        (const float4*)user_emb, (const float4*)item_emb, (ushort4*)xb0,
        W_gc, W_bi, b_gc, b_bi, wgT, wbT, biasSum, bcnt);

    k_count<<<(NGRP + 255) / 256, 256, 0, stream>>>((const intx4*)adj_row, bcnt);
    k_bktscan<<<1, 256, 0, stream>>>(bcnt, bbase0, gbcur);
    k_scatterP<<<(NNZC + 4095) / 4096, 256, 0, stream>>>(
        (const intx4*)adj_row, (const intx4*)adj_col, (const floatx4*)adj_val, gbcur, eb);
    k_csrC<<<NBKT, 256, 0, stream>>>(eb, bbase0, rp, ecv);

    unsigned short* xbs[4] = {xb0, xb1, xb2, xb3};
    const int NB_LAYER = (NTOT + RPB - 1) / RPB;
    for (int k = 0; k < 3; k++) {
        k_spmm<<<NTOT / 4, 256, 0, stream>>>(rp, ecv, xbs[k], side_bf);
        k_layer_mfma<<<NB_LAYER, 256, 0, stream>>>(side_bf, xbs[k], xbs[k + 1],
            wgT + (size_t)k * 4096, wbT + (size_t)k * 4096, biasSum + (size_t)k * 64);
    }
    k_gatherAll<<<(NSLOT * 4) / 4, 256, 0, stream>>>(xb0, xb1, xb2, xb3, users, pos, neg, out);
}